// Round 4
// baseline (30.894 us; speedup 1.0000x reference)
//
#include <hip/hip_runtime.h>
#include <math.h>

// Problem constants (match reference)
constexpr int   BATCH = 32;
constexpr int   S     = 262144;
constexpr int   BLK   = 128;          // samples per filter block
constexpr int   NB    = S / BLK;      // 2048 blocks per batch row
constexpr float SRATE = 44100.0f;
constexpr float FC_MIN = 2000.0f, FC_MAX = 20000.0f;
constexpr float Q_MIN  = 0.1f,    Q_MAX  = 10.0f;

constexpr int WPB     = 32;           // audio blocks per tile
constexpr int TILES   = 2;            // tiles per WG (double-buffered)
constexpr int THREADS = 256;
constexpr int T_X4    = WPB * BLK / 4;   // 1024 float4 of x per tile

typedef float f32x4 __attribute__((ext_vector_type(4)));

// Inline-asm global load: pins issue ORDER (volatile+memory) so our counted
// vmcnt waits are exact. Result regs are only valid after an explicit
// s_waitcnt that ties them as "+v" operands (data-dep fence, rule-18-safe).
#define GLOAD(dst, p)                                                     \
  asm volatile("global_load_dwordx4 %0, %1, off"                          \
               : "=v"(dst) : "v"(p) : "memory")

// Per-tile pipeline stage. VM = vmcnt count that guarantees this tile's
// cp loads AND x-DMA have retired (in-order retirement; younger ops may
// still be in flight -> prefetch survives the barrier).
#define PROCESS(U, VMSTR, R0, R1)                                          \
  do {                                                                     \
    asm volatile("s_waitcnt vmcnt(" VMSTR ")"                              \
                 : "+v"(R0[0]), "+v"(R0[1]), "+v"(R0[2]), "+v"(R0[3]),     \
                   "+v"(R1[0]), "+v"(R1[1]), "+v"(R1[2]), "+v"(R1[3]));    \
    _Pragma("unroll")                                                      \
    for (int k = 0; k < 4; ++k) {                                          \
      float s0 = (R0[k].x + R0[k].y) + (R0[k].z + R0[k].w);                \
      float s1 = (R1[k].x + R1[k].y) + (R1[k].z + R1[k].w);                \
      s0 += __shfl_xor(s0, 1);  s1 += __shfl_xor(s1, 1);                   \
      s0 += __shfl_xor(s0, 2);  s1 += __shfl_xor(s1, 2);                   \
      s0 += __shfl_xor(s0, 4);  s1 += __shfl_xor(s1, 4);                   \
      s0 += __shfl_xor(s0, 8);  s1 += __shfl_xor(s1, 8);                   \
      s0 += __shfl_xor(s0, 16); s1 += __shfl_xor(s1, 16);                  \
      if ((t & 31) == 0) {                                                 \
        const int Bseg = k * 8 + (t >> 5);                                 \
        ms0[U][Bseg] = s0;                                                 \
        ms1[U][Bseg] = s1;                                                 \
      }                                                                    \
    }                                                                      \
    asm volatile("s_waitcnt lgkmcnt(0)\n\ts_barrier" ::: "memory");        \
    if (t < WPB) {                                                         \
      const float m0 = ms0[U][t] * (1.0f / BLK);                           \
      const float m1 = ms1[U][t] * (1.0f / BLK);                           \
      const float fcv = m0 * (FC_MAX - FC_MIN) + FC_MIN;                   \
      const float qv  = m1 * (Q_MAX - Q_MIN) + Q_MIN;                      \
      const int gblk = b * NB + blk0 + (U) * WPB + t;                      \
      fc_out[gblk] = fcv;                                                  \
      q_out[gblk]  = qv;                                                   \
      const float w0 = 6.283185307179586f * fcv / SRATE;                   \
      float sw, cw;                                                        \
      sincosf(w0, &sw, &cw);                                               \
      const float alpha = sw / (2.0f * qv);                                \
      const float a0inv = 1.0f / (1.0f + alpha);                           \
      const float b0c = (1.0f - cw) * 0.5f * a0inv;  /* b2 == b0 */        \
      const float b1c = (1.0f - cw) * a0inv;                               \
      const float a1c = (-2.0f * cw) * a0inv;                              \
      const float a2c = (1.0f - alpha) * a0inv;                            \
      f32x4* xs4u = reinterpret_cast<f32x4*>(xs[U]);                       \
      const int swz = t & 7;                                               \
      float z1 = 0.0f, z2 = 0.0f;                                          \
      _Pragma("unroll 8")                                                  \
      for (int j = 0; j < 32; ++j) {                                       \
        const int a = t * 32 + (j ^ swz);                                  \
        f32x4 xv = xs4u[a];                                                \
        f32x4 yv;                                                          \
        { float xn = xv.x; float y = b0c * xn + z1;                        \
          float z1n = b1c * xn - a1c * y + z2;                             \
          z2 = b0c * xn - a2c * y; z1 = z1n; yv.x = y; }                   \
        { float xn = xv.y; float y = b0c * xn + z1;                        \
          float z1n = b1c * xn - a1c * y + z2;                             \
          z2 = b0c * xn - a2c * y; z1 = z1n; yv.y = y; }                   \
        { float xn = xv.z; float y = b0c * xn + z1;                        \
          float z1n = b1c * xn - a1c * y + z2;                             \
          z2 = b0c * xn - a2c * y; z1 = z1n; yv.z = y; }                   \
        { float xn = xv.w; float y = b0c * xn + z1;                        \
          float z1n = b1c * xn - a1c * y + z2;                             \
          z2 = b0c * xn - a2c * y; z1 = z1n; yv.w = y; }                   \
        xs4u[a] = yv;  /* in-place: each lane owns its row */              \
      }                                                                    \
    }                                                                      \
    asm volatile("s_waitcnt lgkmcnt(0)\n\ts_barrier" ::: "memory");        \
    {                                                                      \
      f32x4* o4 = reinterpret_cast<f32x4*>(out + xbase);                   \
      const f32x4* xs4u = reinterpret_cast<const f32x4*>(xs[U]);           \
      _Pragma("unroll")                                                    \
      for (int k = 0; k < 4; ++k) {                                        \
        const int D  = k * THREADS + t;                                    \
        const int Br = D >> 5;                                             \
        const int jp = D & 31;                                             \
        o4[(U) * T_X4 + Br * 32 + (jp ^ (Br & 7))] = xs4u[D];              \
      }                                                                    \
    }                                                                      \
  } while (0)

__global__ __launch_bounds__(THREADS) void lowpass_kernel(
    const float* __restrict__ x,
    const float* __restrict__ cp,
    float* __restrict__ out,
    float* __restrict__ fc_out,
    float* __restrict__ q_out)
{
    __shared__ float xs[TILES][WPB * BLK];          // 2 x 16 KB
    __shared__ float ms0[TILES][WPB], ms1[TILES][WPB];

    const int t    = threadIdx.x;
    const int wg   = blockIdx.x;                     // 0..1023
    const int b    = wg >> 5;                        // 32 WGs per batch row
    const int blk0 = (wg & 31) * (WPB * TILES);      // 64 blocks per WG

    const size_t xbase = (size_t)b * S + (size_t)blk0 * BLK;   // float index
    const f32x4* x4 = reinterpret_cast<const f32x4*>(x + xbase);
    const f32x4* c0 = reinterpret_cast<const f32x4*>(
        cp + (size_t)b * 2 * S + (size_t)blk0 * BLK);
    const f32x4* c1 = c0 + S / 4;

    f32x4 c0a[4], c1a[4], c0b[4], c1b[4];

    // ---- prologue: issue ALL global traffic up front -------------------
    // issue order (pinned): [DMA x tile0: 4][cp tile0: 8][DMA x tile1: 4][cp tile1: 8]
#pragma unroll
    for (int k = 0; k < 4; ++k) {           // x DMA, tile 0
        const int D = k * THREADS + t, B = D >> 5, jp = D & 31;
        __builtin_amdgcn_global_load_lds(
            (const __attribute__((address_space(1))) void*)(x4 + (B * 32 + (jp ^ (B & 7)))),
            (__attribute__((address_space(3))) void*)(&xs[0][(k * THREADS + (t & ~63)) * 4]),
            16, 0, 0);
    }
#pragma unroll
    for (int k = 0; k < 4; ++k) GLOAD(c0a[k], c0 + k * THREADS + t);
#pragma unroll
    for (int k = 0; k < 4; ++k) GLOAD(c1a[k], c1 + k * THREADS + t);
#pragma unroll
    for (int k = 0; k < 4; ++k) {           // x DMA, tile 1
        const int D = k * THREADS + t, B = D >> 5, jp = D & 31;
        __builtin_amdgcn_global_load_lds(
            (const __attribute__((address_space(1))) void*)(x4 + (T_X4 + B * 32 + (jp ^ (B & 7)))),
            (__attribute__((address_space(3))) void*)(&xs[1][(k * THREADS + (t & ~63)) * 4]),
            16, 0, 0);
    }
#pragma unroll
    for (int k = 0; k < 4; ++k) GLOAD(c0b[k], c0 + T_X4 + k * THREADS + t);
#pragma unroll
    for (int k = 0; k < 4; ++k) GLOAD(c1b[k], c1 + T_X4 + k * THREADS + t);

    // ---- tile 0: vmcnt(12) -> cp0 + DMA0 retired, tile-1 loads in flight
    PROCESS(0, "12", c0a, c1a);
    // ---- tile 1: vmcnt(4) -> all loads retired (4 youngest = out-stores)
    PROCESS(1, "4", c0b, c1b);
}

extern "C" void kernel_launch(void* const* d_in, const int* in_sizes, int n_in,
                              void* d_out, int out_size, void* d_ws, size_t ws_size,
                              hipStream_t stream) {
    const float* x  = (const float*)d_in[0];   // (32, 1, 262144)
    const float* cp = (const float*)d_in[1];   // (32, 2, 262144)

    float* out    = (float*)d_out;                      // 32*262144
    float* fc_out = out + (size_t)BATCH * S;            // 32*2048
    float* q_out  = fc_out + (size_t)BATCH * NB;        // 32*2048

    const int total_blocks = BATCH * NB;                // 65536 audio blocks
    const int grid = total_blocks / (WPB * TILES);      // 1024 workgroups
    lowpass_kernel<<<grid, THREADS, 0, stream>>>(x, cp, out, fc_out, q_out);
}

// Round 5
// 25.677 us; speedup vs baseline: 1.2032x; 1.2032x over previous
//
#include <hip/hip_runtime.h>
#include <math.h>

// Problem constants (match reference)
constexpr int   BATCH = 32;
constexpr int   S     = 262144;
constexpr int   BLK   = 128;          // samples per filter block
constexpr int   NB    = S / BLK;      // 2048 blocks per batch row
constexpr float SRATE = 44100.0f;
constexpr float FC_MIN = 2000.0f, FC_MAX = 20000.0f;
constexpr float Q_MIN  = 0.1f,    Q_MAX  = 10.0f;

// Structure: 32 lanes cooperate on one audio block IN THE COALESCED DOMAIN.
// Lane r holds samples 4r..4r+3 (one float4) — exactly what a coalesced load
// delivers, so there is no transpose, no LDS, no barrier anywhere.
//
// Biquad as linear state recurrence: s=(z1,z2), s' = M s + k x with
//   M = [[-a1, 1], [-a2, 0]],  k = (b1 - a1 b0,  b2 - a2 b0)   (b2 == b0)
// Per lane: local 4-sample pass from s=0 gives u_r (block-local suffix state).
// True incoming state of lane r:  S_r = sum_{j<r} (M^4)^{r-1-j} u_j  — a scan
// with a LANE-UNIFORM matrix, so Kogge-Stone needs only the 2-float state
// shuffled per step; the matrix powers M^4,M^8,..,M^64 are squared locally.

__global__ __launch_bounds__(256) void lowpass_scan_kernel(
    const float4* __restrict__ x4,
    const float4* __restrict__ cp4,
    float4* __restrict__ o4,
    float* __restrict__ fc_out,
    float* __restrict__ q_out)
{
    const int tid  = blockIdx.x * blockDim.x + threadIdx.x;
    const int lane = tid & 63;
    const int r    = lane & 31;            // chunk index within the block
    const int blkg = tid >> 5;             // global audio-block id, 0..65535
    const int b    = blkg >> 11;           // batch row (/ NB)
    const int blkL = blkg & (NB - 1);      // block within batch row

    // float4 indices (all perfectly coalesced across the wave)
    const size_t xi  = (size_t)blkg * 32 + r;                        // x / out
    const size_t c0i = (size_t)b * (2 * S / 4) + (size_t)blkL * 32 + r;

    const float4 xv  = x4[xi];
    const float4 c0v = cp4[c0i];
    const float4 c1v = cp4[c0i + S / 4];

    // ---- control means: tree reduce across the 32-lane segment ----------
    float s0 = (c0v.x + c0v.y) + (c0v.z + c0v.w);
    float s1 = (c1v.x + c1v.y) + (c1v.z + c1v.w);
#pragma unroll
    for (int m = 1; m < 32; m <<= 1) {     // masks <32: stays within segment
        s0 += __shfl_xor(s0, m);
        s1 += __shfl_xor(s1, m);
    }
    const float m0 = s0 * (1.0f / BLK);
    const float m1 = s1 * (1.0f / BLK);

    const float fc = m0 * (FC_MAX - FC_MIN) + FC_MIN;
    const float q  = m1 * (Q_MAX - Q_MIN) + Q_MIN;
    if (r == 0) {                          // one writer per block
        fc_out[blkg] = fc;
        q_out[blkg]  = q;
    }

    // ---- RBJ low-pass coefficients (computed redundantly per lane) -------
    const float w0 = 6.283185307179586f * fc / SRATE;
    float sw, cw;
    sincosf(w0, &sw, &cw);
    const float alpha = sw / (2.0f * q);
    const float a0inv = 1.0f / (1.0f + alpha);
    const float b0c = (1.0f - cw) * 0.5f * a0inv;   // b2 == b0
    const float b1c = (1.0f - cw) * a0inv;
    const float a1c = (-2.0f * cw) * a0inv;
    const float a2c = (1.0f - alpha) * a0inv;
    const float k1  = b1c - a1c * b0c;
    const float k2  = b0c - a2c * b0c;

    // ---- local pass: 4 samples from zero state -> u = (u1,u2) ------------
    float u1 = 0.0f, u2 = 0.0f;
    {
        float xn, t1;
        xn = xv.x; t1 = u2 - a1c * u1 + k1 * xn; u2 = -a2c * u1 + k2 * xn; u1 = t1;
        xn = xv.y; t1 = u2 - a1c * u1 + k1 * xn; u2 = -a2c * u1 + k2 * xn; u1 = t1;
        xn = xv.z; t1 = u2 - a1c * u1 + k1 * xn; u2 = -a2c * u1 + k2 * xn; u1 = t1;
        xn = xv.w; t1 = u2 - a1c * u1 + k1 * xn; u2 = -a2c * u1 + k2 * xn; u1 = t1;
    }

    // ---- P = M^4 via two squarings of M ----------------------------------
    float P00 = -a1c, P01 = 1.0f, P10 = -a2c, P11 = 0.0f;
#define SQUARE_P()                                  \
    {   float q00 = P00 * P00 + P01 * P10;          \
        float q01 = P01 * (P00 + P11);              \
        float q10 = P10 * (P00 + P11);              \
        float q11 = P11 * P11 + P01 * P10;          \
        P00 = q00; P01 = q01; P10 = q10; P11 = q11; }
    SQUARE_P();   // M^2
    SQUARE_P();   // M^4

    // ---- Kogge-Stone inclusive scan: v_r = sum_{j<=r} P^(r-j) u_j --------
    float v1 = u1, v2 = u2;
#define SCAN_STEP(d)                                        \
    {   float w1 = __shfl_up(v1, d, 32);                    \
        float w2 = __shfl_up(v2, d, 32);                    \
        float t1 = v1 + P00 * w1 + P01 * w2;                \
        float t2 = v2 + P10 * w1 + P11 * w2;                \
        v1 = (r >= d) ? t1 : v1;                            \
        v2 = (r >= d) ? t2 : v2; }
    SCAN_STEP(1)  SQUARE_P();   // P -> M^8
    SCAN_STEP(2)  SQUARE_P();   // P -> M^16
    SCAN_STEP(4)  SQUARE_P();   // P -> M^32
    SCAN_STEP(8)  SQUARE_P();   // P -> M^64
    SCAN_STEP(16)
#undef SCAN_STEP
#undef SQUARE_P

    // ---- exclusive shift: incoming state for this lane's 4 samples -------
    float z1 = __shfl_up(v1, 1, 32);
    float z2 = __shfl_up(v2, 1, 32);
    if (r == 0) { z1 = 0.0f; z2 = 0.0f; }

    // ---- final pass: DF2T with true incoming state, emit y ---------------
    float4 yv;
    {
        float xn, y, z1n;
        xn = xv.x; y = b0c * xn + z1;
        z1n = b1c * xn - a1c * y + z2; z2 = b0c * xn - a2c * y; z1 = z1n; yv.x = y;
        xn = xv.y; y = b0c * xn + z1;
        z1n = b1c * xn - a1c * y + z2; z2 = b0c * xn - a2c * y; z1 = z1n; yv.y = y;
        xn = xv.z; y = b0c * xn + z1;
        z1n = b1c * xn - a1c * y + z2; z2 = b0c * xn - a2c * y; z1 = z1n; yv.z = y;
        xn = xv.w; y = b0c * xn + z1;
        z1n = b1c * xn - a1c * y + z2; z2 = b0c * xn - a2c * y; z1 = z1n; yv.w = y;
    }
    o4[xi] = yv;
}

extern "C" void kernel_launch(void* const* d_in, const int* in_sizes, int n_in,
                              void* d_out, int out_size, void* d_ws, size_t ws_size,
                              hipStream_t stream) {
    const float4* x4  = (const float4*)d_in[0];   // (32, 1, 262144)
    const float4* cp4 = (const float4*)d_in[1];   // (32, 2, 262144)

    float* out    = (float*)d_out;                      // 32*262144
    float* fc_out = out + (size_t)BATCH * S;            // 32*2048
    float* q_out  = fc_out + (size_t)BATCH * NB;        // 32*2048

    // 32 lanes per audio block: 65536 blocks * 32 = 2,097,152 threads
    const int total_threads = BATCH * NB * 32;
    lowpass_scan_kernel<<<total_threads / 256, 256, 0, stream>>>(
        x4, cp4, (float4*)out, fc_out, q_out);
}